// Round 2
// baseline (227.808 us; speedup 1.0000x reference)
//
#include <hip/hip_runtime.h>
#include <hip/hip_bf16.h>
#include <math.h>

#define EPSF 1e-8f

typedef __attribute__((ext_vector_type(8))) short bf16x8;
typedef __attribute__((ext_vector_type(4))) float f32x4;

static __device__ __forceinline__ unsigned short f2bf(float f) {
    __hip_bfloat16 h = __float2bfloat16(f);
    return *reinterpret_cast<unsigned short*>(&h);
}
static __device__ __forceinline__ float bf2f(unsigned short u) {
    __hip_bfloat16 h;
    *reinterpret_cast<unsigned short*>(&h) = u;
    return __bfloat162float(h);
}

// async global->LDS, 16B/lane: wave-uniform LDS base + lane*16.
static __device__ __forceinline__ void async16(void* lds, const void* g) {
    __builtin_amdgcn_global_load_lds(
        (const __attribute__((address_space(1))) unsigned int*)g,
        (__attribute__((address_space(3))) unsigned int*)lds, 16, 0, 0);
}

// ---------------------------------------------------------------------------
// FRAGMENT-ORDER layout: [R,K] stored as 1KB chunks; chunk = (r/16)*(K/32)
// + (k/32); lane l holds [r=l&15][k=(l>>4)*8..+8] at elem offset l*8.
// ---------------------------------------------------------------------------

// ---------------------------------------------------------------------------
// R16 slim prep (fused path): weights only + zero gl/gy/cnt. X conversion
// moved into mlp_fused (reads raw f32) -- kills the 48MB XF round-trip.
// ---------------------------------------------------------------------------
__global__ __launch_bounds__(256) void prep_slim(
    const float* __restrict__ W1, const float* __restrict__ W2,
    unsigned short* __restrict__ w1h, unsigned short* __restrict__ w2h,
    float* __restrict__ gl, float* __restrict__ gy, int* __restrict__ cnt)
{
    const int t = threadIdx.x;
    const int b = blockIdx.x;
    if (b < 512) {
        // W1 [256,512] -> [512 rows, 256 k], single bf16 plane
        int idx = b * 256 + t;
        int n = idx >> 8, k = idx & 255;
        float w = W1[(size_t)k * 512 + n];
        int chunk = (n >> 4) * 8 + (k >> 5);
        int lne = (n & 15) | (((k >> 3) & 3) << 4);
        w1h[chunk * 512 + lne * 8 + (k & 7)] = f2bf(w);
    } else if (b < 768) {
        // W2 [512,128] -> [128 rows, 512 k], single bf16 plane
        int idx = (b - 512) * 256 + t;
        int n = idx >> 9, k = idx & 511;
        float w = W2[(size_t)k * 128 + n];
        int chunk = (n >> 4) * 16 + (k >> 5);
        int lne = (n & 15) | (((k >> 3) & 3) << 4);
        w2h[chunk * 512 + lne * 8 + (k & 7)] = f2bf(w);
    } else {
        float4 z = make_float4(0.f, 0.f, 0.f, 0.f);
        ((float4*)gl)[t] = z;     // 256 float4 = 1024 floats
        ((float4*)gy)[t] = z;
        if (t < 16) cnt[t] = 0;
    }
}

// ---------------------------------------------------------------------------
// Full prep (fallback path only): old R14 behavior + cnt zeroing.
// ---------------------------------------------------------------------------
__global__ __launch_bounds__(256) void prep_full(
    const float* __restrict__ subx, const float* __restrict__ x,
    const float* __restrict__ W1, const float* __restrict__ W2,
    unsigned short* __restrict__ XF,
    unsigned short* __restrict__ w1h, unsigned short* __restrict__ w2h,
    float* __restrict__ gl, float* __restrict__ gy, float* __restrict__ nrm,
    int* __restrict__ cnt, int M, int nsubrow, int nsplitblk)
{
    __shared__ __align__(16) unsigned short sX[8192];
    const int t = threadIdx.x;
    const int b = blockIdx.x;

    if (b < nsplitblk) {
        int gi = b * 256 + t;
        float4 z = make_float4(0.f, 0.f, 0.f, 0.f);
        if (gi < 512) {
            if (gi < 256) ((float4*)gl)[gi] = z;
            else          ((float4*)gy)[gi - 256] = z;
        }
        if (gi < (M + 3) / 4) ((float4*)nrm)[gi] = z;
        if (b == 0 && t < 16) cnt[t] = 0;

        const int rbase = b * 32;
        const int rows = min(32, M - rbase);
        #pragma unroll
        for (int it = 0; it < 8; ++it) {
            int flat = it * 256 + t;
            int row = flat >> 6;
            int k = (flat & 63) * 4;
            if (row < rows) {
                int grow = rbase + row;
                const float* src = (grow < nsubrow)
                    ? subx + (size_t)grow * 256 + k
                    : x + (size_t)(grow - nsubrow) * 256 + k;
                float4 v = *(const float4*)src;
                unsigned short h0 = f2bf(v.x), h1 = f2bf(v.y), h2 = f2bf(v.z), h3 = f2bf(v.w);
                uint2 hp;
                hp.x = ((unsigned)h1 << 16) | h0;  hp.y = ((unsigned)h3 << 16) | h2;
                int chunk = (row >> 4) * 8 + (k >> 5);
                int lne = (row & 15) | (((k >> 3) & 3) << 4);
                *(uint2*)&sX[chunk * 512 + lne * 8 + (k & 7)] = hp;
            }
        }
        __syncthreads();
        const int cvalid = (rows >> 4) * 8;
        const size_t base = (size_t)rbase * 256;
        #pragma unroll
        for (int it = 0; it < 4; ++it) {
            int flat = it * 256 + t;
            if ((flat >> 6) < cvalid)
                *(bf16x8*)&XF[base + flat * 8] = *(const bf16x8*)&sX[flat * 8];
        }
    } else if (b < nsplitblk + 512) {
        int idx = (b - nsplitblk) * 256 + t;
        int n = idx >> 8, k = idx & 255;
        float w = W1[(size_t)k * 512 + n];
        int chunk = (n >> 4) * 8 + (k >> 5);
        int lne = (n & 15) | (((k >> 3) & 3) << 4);
        w1h[chunk * 512 + lne * 8 + (k & 7)] = f2bf(w);
    } else {
        int idx = (b - nsplitblk - 512) * 256 + t;
        int n = idx >> 9, k = idx & 511;
        float w = W2[(size_t)k * 128 + n];
        int chunk = (n >> 4) * 16 + (k >> 5);
        int lne = (n & 15) | (((k >> 3) & 3) << 4);
        w2h[chunk * 512 + lne * 8 + (k & 7)] = f2bf(w);
    }
}

// ---------------------------------------------------------------------------
// Fused MLP (R16): both layers in one kernel; A-fragments converted from
// raw f32 in-register (bit-identical f2bf => absmax unchanged). z1 lives in
// a 64KB XOR-swizzled LDS tile; W1/W2 bf16 frags stream through a 2x32KB
// double buffer with counted vmcnt(8). nrm: direct store.
// ---------------------------------------------------------------------------
static __device__ __forceinline__ void stage_chunk(
    unsigned short* dst, const unsigned short* w1f, const unsigned short* w2f,
    int s, int wave, int lane)
{
    #pragma unroll
    for (int q = 0; q < 8; ++q) {
        int fl = wave * 8 + q;
        const unsigned short* src;
        if (s < 8) src = w1f + (size_t)s * 16384 + fl * 512;              // 64n W1 slice
        else       src = w2f + ((size_t)((fl & 7) * 16 + (s - 8) * 4 + (fl >> 3))) * 512; // 4-kslice W2
        async16(dst + fl * 512, src + lane * 8);
    }
}

__global__ __launch_bounds__(256) void mlp_fused(
    const float* __restrict__ subx, const float* __restrict__ x,
    const unsigned short* __restrict__ W1F,
    const unsigned short* __restrict__ W2F,
    const float* __restrict__ b1, const float* __restrict__ b2,
    unsigned short* __restrict__ embF, float* __restrict__ nrm,
    int M, int nsub)
{
    extern __shared__ __align__(16) char smem[];       // 131072 B dynamic
    unsigned short* buf0 = (unsigned short*)(smem + 65536);
    unsigned short* buf1 = (unsigned short*)(smem + 65536 + 32768);

    const int t = threadIdx.x, wave = t >> 6, lane = t & 63;
    const int quad = lane >> 4, lq = lane & 15;
    const int m0 = blockIdx.x * 64;
    const int lastch = (M >> 4) - 1;
    const int mh = wave >> 1, np = wave & 1;

    // ---- preloads: direct f32 -> bf16 fragment conversion (no XF).
    // Frag layout: lane holds row lq, k = kc*32 + quad*8 .. +8.
    bf16x8 fA[2][8];
    #pragma unroll
    for (int mi = 0; mi < 2; ++mi) {
        int gmc = min((m0 >> 4) + mh * 2 + mi, lastch);
        int grow = gmc * 16 + lq;
        const float* src = (grow < nsub)
            ? subx + (size_t)grow * 256
            : x + (size_t)(grow - nsub) * 256;
        #pragma unroll
        for (int kc = 0; kc < 8; ++kc) {
            const float* p = src + kc * 32 + quad * 8;
            float4 v0 = *(const float4*)p;
            float4 v1 = *(const float4*)(p + 4);
            fA[mi][kc] = (bf16x8){
                (short)f2bf(v0.x), (short)f2bf(v0.y), (short)f2bf(v0.z), (short)f2bf(v0.w),
                (short)f2bf(v1.x), (short)f2bf(v1.y), (short)f2bf(v1.z), (short)f2bf(v1.w)};
        }
    }
    float b1v[16];
    #pragma unroll
    for (int i = 0; i < 16; ++i)
        b1v[i] = b1[(i >> 1) * 64 + (np * 2 + (i & 1)) * 16 + lq];
    float b2v[8];
    #pragma unroll
    for (int i = 0; i < 8; ++i) b2v[i] = b2[i * 16 + lq];

    f32x4 acc2[8];
    #pragma unroll
    for (int i = 0; i < 8; ++i) acc2[i] = (f32x4){0.f, 0.f, 0.f, 0.f};

    __syncthreads();   // drains preload vmcnt to 0; in-loop vmcnt counting exact

    stage_chunk(buf0, W1F, W2F, 0, wave, lane);
    #pragma unroll
    for (int c = 0; c < 12; ++c) {
        if (c < 11) {
            stage_chunk(((c + 1) & 1) ? buf1 : buf0, W1F, W2F, c + 1, wave, lane);
            asm volatile("s_waitcnt vmcnt(8)" ::: "memory");   // chunk c landed
        } else {
            asm volatile("s_waitcnt vmcnt(0)" ::: "memory");
        }
        __builtin_amdgcn_s_barrier();
        const unsigned short* sW = (c & 1) ? buf1 : buf0;

        if (c < 8) {
            // ---- layer 1: z1[:, c*64 .. c*64+64) = relu(X@W1^T + b1)
            f32x4 a1[2][2];
            #pragma unroll
            for (int mi = 0; mi < 2; ++mi)
                #pragma unroll
                for (int nl = 0; nl < 2; ++nl) a1[mi][nl] = (f32x4){0.f, 0.f, 0.f, 0.f};
            __builtin_amdgcn_s_setprio(1);
            #pragma unroll
            for (int kc = 0; kc < 8; ++kc) {
                #pragma unroll
                for (int nl = 0; nl < 2; ++nl) {
                    bf16x8 fB = *(const bf16x8*)&sW[((np * 2 + nl) * 8 + kc) * 512 + lane * 8];
                    #pragma unroll
                    for (int mi = 0; mi < 2; ++mi)
                        a1[mi][nl] = __builtin_amdgcn_mfma_f32_16x16x32_bf16(
                            fA[mi][kc], fB, a1[mi][nl], 0, 0, 0);
                }
            }
            __builtin_amdgcn_s_setprio(0);
            #pragma unroll
            for (int mi = 0; mi < 2; ++mi) {
                #pragma unroll
                for (int nl = 0; nl < 2; ++nl) {
                    int col = c * 64 + (np * 2 + nl) * 16 + lq;
                    #pragma unroll
                    for (int r = 0; r < 4; ++r) {
                        int row = (mh * 2 + mi) * 16 + quad * 4 + r;
                        float v = fmaxf(a1[mi][nl][r] + b1v[c * 2 + nl], 0.f);
                        int off = (row * 1024 + col * 2) ^ ((row & 7) << 4);
                        *(unsigned short*)(smem + off) = f2bf(v);
                    }
                }
            }
        } else {
            // ---- layer 2: acc2 += z1[rows, kq] @ W2^T[:, kq]
            const int Q = c - 8;
            const int row = wave * 16 + lq;
            const int sw = (row & 7) << 4;
            __builtin_amdgcn_s_setprio(1);
            #pragma unroll
            for (int gs = 0; gs < 4; ++gs) {
                int k2c = Q * 4 + gs;
                int offa = (row * 1024 + (k2c * 32 + quad * 8) * 2) ^ sw;
                bf16x8 a2 = *(const bf16x8*)(smem + offa);
                #pragma unroll
                for (int nc = 0; nc < 8; ++nc) {
                    bf16x8 fB = *(const bf16x8*)&sW[(gs * 8 + nc) * 512 + lane * 8];
                    acc2[nc] = __builtin_amdgcn_mfma_f32_16x16x32_bf16(a2, fB, acc2[nc], 0, 0, 0);
                }
            }
            __builtin_amdgcn_s_setprio(0);
        }
        asm volatile("s_waitcnt lgkmcnt(0)" ::: "memory");
        __builtin_amdgcn_s_barrier();
    }

    // ---- epilogue: bias2+relu -> ctile -> frag-order emb + nrm
    __syncthreads();
    unsigned short* ct = (unsigned short*)smem;   // [64][136] bf16
    #pragma unroll
    for (int nc = 0; nc < 8; ++nc) {
        #pragma unroll
        for (int r = 0; r < 4; ++r) {
            int row = wave * 16 + quad * 4 + r;
            float v = fmaxf(acc2[nc][r] + b2v[nc], 0.f);
            ct[row * 136 + nc * 16 + lq] = f2bf(v);
        }
    }
    __syncthreads();
    #pragma unroll
    for (int it = 0; it < 4; ++it) {
        int flat = it * 256 + t;
        int lc = flat >> 6, l = flat & 63;
        int mcl = lc >> 2, kc = lc & 3;
        int gmc2 = (m0 >> 4) + mcl;
        if (gmc2 * 16 < M) {
            bf16x8 v = *(const bf16x8*)&ct[(mcl * 16 + (l & 15)) * 136 + kc * 32 + (l >> 4) * 8];
            *(bf16x8*)&embF[((size_t)gmc2 * 4 + kc) * 512 + l * 8] = v;
        }
    }
    if (t < 64) {
        int gm = m0 + t;
        if (gm < M) {
            float s = 0.f;
            #pragma unroll
            for (int seg = 0; seg < 16; ++seg) {
                bf16x8 v = *(const bf16x8*)&ct[t * 136 + seg * 8];
                #pragma unroll
                for (int e = 0; e < 8; ++e) {
                    float f = bf2f((unsigned short)v[e]);
                    s = fmaf(f, f, s);
                }
            }
            nrm[gm] = s;
        }
    }
}

// ---------------------------------------------------------------------------
// Fallback GEMMs (unchanged; used only if 128KB dynamic-LDS opt-in fails).
// ---------------------------------------------------------------------------
__global__ __launch_bounds__(256) void gemm_l1(
    const unsigned short* __restrict__ XF,
    const unsigned short* __restrict__ BhF,
    const float* __restrict__ bias, unsigned short* __restrict__ z1F, int M)
{
    __shared__ __align__(16) unsigned short sB[16384];

    const int nb = gridDim.x;
    const int per = nb >> 3, rem = nb & 7;
    const int xcd = blockIdx.x & 7, slot = blockIdx.x >> 3;
    const int newbid = xcd * per + min(xcd, rem) + slot;
    const int m0 = (newbid >> 3) * 128, n0 = (newbid & 7) * 64;

    const int t = threadIdx.x, wave = t >> 6, lane = t & 63;
    const int quad = lane >> 4, lq = lane & 15;
    const int lastch = (M >> 4) - 1;

    #pragma unroll
    for (int q = 0; q < 8; ++q) {
        int c = wave * 8 + q;
        int nc = c >> 3, kc = c & 7;
        const unsigned short* src = BhF
            + ((size_t)((n0 >> 4) + nc)) * 4096 + kc * 512 + lane * 8;
        async16(sB + c * 512, src);
    }

    const unsigned short* pA[2];
    #pragma unroll
    for (int mi = 0; mi < 2; ++mi) {
        int mc = min((m0 >> 4) + wave * 2 + mi, lastch);
        pA[mi] = XF + (size_t)mc * 4096 + lane * 8;
    }

    f32x4 acc[2][4];
    #pragma unroll
    for (int i = 0; i < 2; ++i)
        #pragma unroll
        for (int j = 0; j < 4; ++j) acc[i][j] = (f32x4){0.f, 0.f, 0.f, 0.f};

    __syncthreads();

    #pragma unroll
    for (int kc = 0; kc < 8; ++kc) {
        bf16x8 fA[2];
        #pragma unroll
        for (int mi = 0; mi < 2; ++mi)
            fA[mi] = *(const bf16x8*)(pA[mi] + kc * 512);
        #pragma unroll
        for (int ni = 0; ni < 4; ++ni) {
            bf16x8 fB = *(const bf16x8*)&sB[(ni * 8 + kc) * 512 + lane * 8];
            #pragma unroll
            for (int mi = 0; mi < 2; ++mi)
                acc[mi][ni] = __builtin_amdgcn_mfma_f32_16x16x32_bf16(fA[mi], fB, acc[mi][ni], 0, 0, 0);
        }
    }

    __syncthreads();
    unsigned short* ctile = sB;
    float bv[4];
    #pragma unroll
    for (int ni = 0; ni < 4; ++ni) bv[ni] = bias[n0 + ni * 16 + lq];
    #pragma unroll
    for (int mi = 0; mi < 2; ++mi)
        #pragma unroll
        for (int ni = 0; ni < 4; ++ni)
            #pragma unroll
            for (int r = 0; r < 4; ++r) {
                float v = fmaxf(acc[mi][ni][r] + bv[ni], 0.f);
                ctile[(wave * 32 + mi * 16 + quad * 4 + r) * 72 + ni * 16 + lq] = f2bf(v);
            }
    __syncthreads();
    #pragma unroll
    for (int it = 0; it < 4; ++it) {
        int flat = it * 256 + t;
        int c = flat >> 6, l = flat & 63;
        int mcl = c >> 1, kc2 = c & 1;
        int gmc = (m0 >> 4) + mcl;
        if (gmc * 16 < M) {
            bf16x8 v = *(const bf16x8*)&ctile[(mcl * 16 + (l & 15)) * 72 + kc2 * 32 + (l >> 4) * 8];
            *(bf16x8*)&z1F[((size_t)gmc * 16 + (n0 >> 5) + kc2) * 512 + l * 8] = v;
        }
    }
}

__global__ __launch_bounds__(256) void gemm_l2_norm(
    const unsigned short* __restrict__ AF,
    const unsigned short* __restrict__ BhF,
    const float* __restrict__ bias, unsigned short* __restrict__ embF,
    float* __restrict__ nrm, int M)
{
    __shared__ __align__(16) unsigned short sB[18432];

    const int nb = gridDim.x;
    const int per = nb >> 3, rem = nb & 7;
    const int xcd = blockIdx.x & 7, slot = blockIdx.x >> 3;
    const int newbid = xcd * per + min(xcd, rem) + slot;
    const int m0 = (newbid >> 2) * 256, n0 = (newbid & 3) * 32;

    const int t = threadIdx.x, wave = t >> 6, lane = t & 63;
    const int quad = lane >> 4, lq = lane & 15;
    const int lastch = (M >> 4) - 1;

    #pragma unroll
    for (int q = 0; q < 8; ++q) {
        int c = wave * 8 + q;
        int nc = c >> 4, kc = c & 15;
        const unsigned short* src = BhF
            + ((size_t)((n0 >> 4) + nc)) * 8192 + kc * 512 + lane * 8;
        async16(sB + c * 512, src);
    }

    const unsigned short* pA[4];
    #pragma unroll
    for (int mi = 0; mi < 4; ++mi) {
        int mc = min((m0 >> 4) + wave * 4 + mi, lastch);
        pA[mi] = AF + (size_t)mc * 8192 + lane * 8;
    }

    f32x4 acc[4][2];
    #pragma unroll
    for (int i = 0; i < 4; ++i)
        #pragma unroll
        for (int j = 0; j < 2; ++j) acc[i][j] = (f32x4){0.f, 0.f, 0.f, 0.f};

    __syncthreads();

    #pragma unroll 4
    for (int kc = 0; kc < 16; ++kc) {
        bf16x8 fA[4];
        #pragma unroll
        for (int mi = 0; mi < 4; ++mi)
            fA[mi] = *(const bf16x8*)(pA[mi] + kc * 512);
        #pragma unroll
        for (int ni = 0; ni < 2; ++ni) {
            bf16x8 fB = *(const bf16x8*)&sB[(ni * 16 + kc) * 512 + lane * 8];
            #pragma unroll
            for (int mi = 0; mi < 4; ++mi)
                acc[mi][ni] = __builtin_amdgcn_mfma_f32_16x16x32_bf16(fA[mi], fB, acc[mi][ni], 0, 0, 0);
        }
    }

    __syncthreads();
    unsigned short* ctile = sB;
    float bv[2];
    #pragma unroll
    for (int ni = 0; ni < 2; ++ni) bv[ni] = bias[n0 + ni * 16 + lq];
    #pragma unroll
    for (int mi = 0; mi < 4; ++mi)
        #pragma unroll
        for (int ni = 0; ni < 2; ++ni)
            #pragma unroll
            for (int r = 0; r < 4; ++r) {
                float v = fmaxf(acc[mi][ni][r] + bv[ni], 0.f);
                ctile[(wave * 64 + mi * 16 + quad * 4 + r) * 36 + ni * 16 + lq] = f2bf(v);
            }
    __syncthreads();

    #pragma unroll
    for (int it = 0; it < 4; ++it) {
        int flat = it * 256 + t;
        int c = flat >> 6, l = flat & 63;
        int gmc = (m0 >> 4) + c;
        if (gmc * 16 < M) {
            bf16x8 v = *(const bf16x8*)&ctile[(c * 16 + (l & 15)) * 36 + (l >> 4) * 8];
            *(bf16x8*)&embF[((size_t)gmc * 4 + (n0 >> 5)) * 512 + l * 8] = v;
        }
    }
    int gm = m0 + t;
    if (gm < M) {
        float s = 0.f;
        #pragma unroll
        for (int seg = 0; seg < 4; ++seg) {
            bf16x8 v = *(const bf16x8*)&ctile[t * 36 + seg * 8];
            #pragma unroll
            for (int e = 0; e < 8; ++e) {
                float f = bf2f((unsigned short)v[e]);
                s = fmaf(f, f, s);
            }
        }
        atomicAdd(&nrm[gm], s);
    }
}

// ---------------------------------------------------------------------------
// Flash NCA + folded finalize: last j-split block per i-group (device-scope
// ticket) computes out = gy/gl via atomic reads (cross-XCD safe).
// ---------------------------------------------------------------------------
__global__ __launch_bounds__(256) void nca_flash_mfma(
    const unsigned short* __restrict__ embF, const float* __restrict__ nrm,
    const float* __restrict__ y, float* __restrict__ gl, float* __restrict__ gy,
    float* __restrict__ out, int* __restrict__ cnt, int N, int jspan)
{
    __shared__ __align__(16) unsigned short sB[16384];
    __shared__ float s2s[128], ys[128];
    __shared__ int sdone;

    const int t = threadIdx.x, wave = t >> 6, lane = t & 63;
    const int quad = lane >> 4, lq = lane & 15;
    const int i0 = blockIdx.x * 64;
    const int j0base = blockIdx.y * jspan;
    const int jend = min(j0base + jspan, N);

    bf16x8 fa[4];
    const int hc = ((N + i0) >> 4) + wave;
    #pragma unroll
    for (int kk = 0; kk < 4; ++kk)
        fa[kk] = *(const bf16x8*)&embF[((size_t)hc * 4 + kk) * 512 + lane * 8];
    float myh2[4];
    #pragma unroll
    for (int r = 0; r < 4; ++r) myh2[r] = nrm[N + i0 + wave * 16 + quad * 4 + r];

    float lacc[4] = {0.f, 0.f, 0.f, 0.f};
    float yacc[4] = {0.f, 0.f, 0.f, 0.f};

    for (int j0 = j0base; j0 < jend; j0 += 128) {
        __syncthreads();
        #pragma unroll
        for (int q = 0; q < 8; ++q) {
            int c = wave * 8 + q;
            async16(sB + c * 512,
                    embF + ((size_t)(j0 >> 4) * 4 + c) * 512 + lane * 8);
        }
        if (t < 128) {
            int j = j0 + t;
            s2s[t] = (j < jend) ? nrm[j] : 1e30f;   // OOB -> p = 0
            ys[t]  = (j < jend) ? y[j] : 0.f;
        }
        __syncthreads();

        f32x4 acc[8];
        #pragma unroll
        for (int jt = 0; jt < 8; ++jt) acc[jt] = (f32x4){0.f, 0.f, 0.f, 0.f};
        #pragma unroll
        for (int kk = 0; kk < 4; ++kk) {
            #pragma unroll
            for (int jt = 0; jt < 8; ++jt) {
                bf16x8 b = *(const bf16x8*)&sB[(jt * 4 + kk) * 512 + lane * 8];
                acc[jt] = __builtin_amdgcn_mfma_f32_16x16x32_bf16(fa[kk], b, acc[jt], 0, 0, 0);
            }
        }

        #pragma unroll
        for (int jt = 0; jt < 8; ++jt) {
            int col = jt * 16 + lq;
            float ss = s2s[col];
            float sy = ys[col];
            #pragma unroll
            for (int r = 0; r < 4; ++r) {
                float d2 = myh2[r] + ss - 2.f * acc[jt][r];
                float d  = sqrtf(fmaxf(d2, 0.f) + EPSF);
                float p  = __expf(-d);
                lacc[r] += p;
                yacc[r]  = fmaf(p, sy, yacc[r]);
            }
        }
    }

    #pragma unroll
    for (int r = 0; r < 4; ++r) {
        #pragma unroll
        for (int off = 8; off > 0; off >>= 1) {
            lacc[r] += __shfl_down(lacc[r], off, 16);
            yacc[r] += __shfl_down(yacc[r], off, 16);
        }
    }
    if (lq == 0) {
        int row = i0 + wave * 16 + quad * 4;
        #pragma unroll
        for (int r = 0; r < 4; ++r) {
            atomicAdd(&gl[row + r], lacc[r]);
            atomicAdd(&gy[row + r], yacc[r]);
        }
    }

    // ---- folded finalize: last block for this i-group divides.
    __threadfence();
    __syncthreads();            // all waves' atomics drained (vmcnt=0) first
    if (t == 0)
        sdone = (atomicAdd(&cnt[blockIdx.x], 1) == (int)gridDim.y - 1) ? 1 : 0;
    __syncthreads();
    if (sdone) {
        __threadfence();
        if (t < 64) {
            int i = i0 + t;
            float l  = atomicAdd(&gl[i], 0.f);   // coherent read
            float yv = atomicAdd(&gy[i], 0.f);
            out[i] = yv / l;
        }
    }
}

// ---------------------------------------------------------------------------
static int g_fused_ok = -1;

extern "C" void kernel_launch(void* const* d_in, const int* in_sizes, int n_in,
                              void* d_out, int out_size, void* d_ws, size_t ws_size,
                              hipStream_t stream)
{
    const float* x    = (const float*)d_in[0];  // [1024,256]
    const float* subx = (const float*)d_in[1];  // [30000,256]
    const float* suby = (const float*)d_in[2];  // [30000]
    const float* W1   = (const float*)d_in[3];  // [256,512]
    const float* b1   = (const float*)d_in[4];  // [512]
    const float* W2   = (const float*)d_in[5];  // [512,128]
    const float* b2   = (const float*)d_in[6];  // [128]
    float* out = (float*)d_out;                 // [1024]

    const int B = 1024, N = 30000, D = 256, H1 = 512, H2 = 128;
    const int M = N + B;  // 31024

    char* wsb = (char*)d_ws;
    size_t off = 0;
    auto alloc = [&](size_t bytes) -> char* {
        char* p = wsb + off;
        off += (bytes + 255) & ~(size_t)255;
        return p;
    };
    unsigned short* cx   = (unsigned short*)alloc((size_t)M * D * 2);   // fallback only
    unsigned short* w1hT = (unsigned short*)alloc((size_t)H1 * D * 2);
    unsigned short* w2hT = (unsigned short*)alloc((size_t)H2 * H1 * 2);
    unsigned short* z1   = (unsigned short*)alloc((size_t)M * H1 * 2);  // fallback only
    unsigned short* emb  = (unsigned short*)alloc((size_t)M * H2 * 2);
    float* nrm = (float*)alloc((size_t)M * 4);
    float* gl  = (float*)alloc((size_t)B * 4);
    float* gy  = (float*)alloc((size_t)B * 4);
    int*   cnt = (int*)alloc(64);
    (void)ws_size; (void)in_sizes; (void)n_in; (void)out_size;

    if (g_fused_ok < 0) {
        hipError_t e = hipFuncSetAttribute((const void*)mlp_fused,
            hipFuncAttributeMaxDynamicSharedMemorySize, 131072);
        g_fused_ok = (e == hipSuccess) ? 1 : 0;
    }

    dim3 blk(256);
    const int JSPAN = 512;
    const int NSPLIT = (N + JSPAN - 1) / JSPAN;  // 59

    if (g_fused_ok) {
        // 3 launches total
        prep_slim<<<dim3(769), blk, 0, stream>>>(W1, W2, w1hT, w2hT, gl, gy, cnt);
        mlp_fused<<<dim3((M + 63) / 64), blk, 131072, stream>>>(
            subx, x, w1hT, w2hT, b1, b2, emb, nrm, M, N);
    } else {
        const int NSPLITBLK = (M + 31) / 32;                 // 970
        prep_full<<<dim3(NSPLITBLK + 512 + 256), blk, 0, stream>>>(
            subx, x, W1, W2, cx, w1hT, w2hT, gl, gy, nrm, cnt, M, N, NSPLITBLK);
        gemm_l1<<<dim3(((M + 127) / 128) * (H1 / 64)), blk, 0, stream>>>(
            cx, w1hT, b1, z1, M);
        gemm_l2_norm<<<dim3(((M + 255) / 256) * (H2 / 32)), blk, 0, stream>>>(
            z1, w2hT, b2, emb, nrm, M);
    }

    nca_flash_mfma<<<dim3(B / 64, NSPLIT), blk, 0, stream>>>(
        emb, nrm, suby, gl, gy, out, cnt, N, JSPAN);
}

// Round 3
// 148.636 us; speedup vs baseline: 1.5327x; 1.5327x over previous
//
#include <hip/hip_runtime.h>
#include <hip/hip_bf16.h>
#include <math.h>

#define EPSF 1e-8f

typedef __attribute__((ext_vector_type(8))) short bf16x8;
typedef __attribute__((ext_vector_type(4))) float f32x4;

static __device__ __forceinline__ unsigned short f2bf(float f) {
    __hip_bfloat16 h = __float2bfloat16(f);
    return *reinterpret_cast<unsigned short*>(&h);
}
static __device__ __forceinline__ float bf2f(unsigned short u) {
    __hip_bfloat16 h;
    *reinterpret_cast<unsigned short*>(&h) = u;
    return __bfloat162float(h);
}

// async global->LDS, 16B/lane: wave-uniform LDS base + lane*16.
static __device__ __forceinline__ void async16(void* lds, const void* g) {
    __builtin_amdgcn_global_load_lds(
        (const __attribute__((address_space(1))) unsigned int*)g,
        (__attribute__((address_space(3))) unsigned int*)lds, 16, 0, 0);
}

// ---------------------------------------------------------------------------
// FRAGMENT-ORDER layout: [R,K] stored as 1KB chunks; chunk = (r/16)*(K/32)
// + (k/32); lane l holds [r=l&15][k=(l>>4)*8..+8] at elem offset l*8.
// ---------------------------------------------------------------------------

// ---------------------------------------------------------------------------
// Slim prep (fused path): weights only + zero gl/gy. X conversion lives in
// mlp_fused (reads raw f32). R2 lesson: do NOT fold finalize into nca --
// device-scope fences (cross-XCD L2 writeback) cost ~80us across 944 blocks.
// ---------------------------------------------------------------------------
__global__ __launch_bounds__(256) void prep_slim(
    const float* __restrict__ W1, const float* __restrict__ W2,
    unsigned short* __restrict__ w1h, unsigned short* __restrict__ w2h,
    float* __restrict__ gl, float* __restrict__ gy)
{
    const int t = threadIdx.x;
    const int b = blockIdx.x;
    if (b < 512) {
        // W1 [256,512] -> [512 rows, 256 k], single bf16 plane
        int idx = b * 256 + t;
        int n = idx >> 8, k = idx & 255;
        float w = W1[(size_t)k * 512 + n];
        int chunk = (n >> 4) * 8 + (k >> 5);
        int lne = (n & 15) | (((k >> 3) & 3) << 4);
        w1h[chunk * 512 + lne * 8 + (k & 7)] = f2bf(w);
    } else if (b < 768) {
        // W2 [512,128] -> [128 rows, 512 k], single bf16 plane
        int idx = (b - 512) * 256 + t;
        int n = idx >> 9, k = idx & 511;
        float w = W2[(size_t)k * 128 + n];
        int chunk = (n >> 4) * 16 + (k >> 5);
        int lne = (n & 15) | (((k >> 3) & 3) << 4);
        w2h[chunk * 512 + lne * 8 + (k & 7)] = f2bf(w);
    } else {
        float4 z = make_float4(0.f, 0.f, 0.f, 0.f);
        ((float4*)gl)[t] = z;     // 256 float4 = 1024 floats
        ((float4*)gy)[t] = z;
    }
}

// ---------------------------------------------------------------------------
// Full prep (fallback path only): old R14 behavior.
// ---------------------------------------------------------------------------
__global__ __launch_bounds__(256) void prep_full(
    const float* __restrict__ subx, const float* __restrict__ x,
    const float* __restrict__ W1, const float* __restrict__ W2,
    unsigned short* __restrict__ XF,
    unsigned short* __restrict__ w1h, unsigned short* __restrict__ w2h,
    float* __restrict__ gl, float* __restrict__ gy, float* __restrict__ nrm,
    int M, int nsubrow, int nsplitblk)
{
    __shared__ __align__(16) unsigned short sX[8192];
    const int t = threadIdx.x;
    const int b = blockIdx.x;

    if (b < nsplitblk) {
        int gi = b * 256 + t;
        float4 z = make_float4(0.f, 0.f, 0.f, 0.f);
        if (gi < 512) {
            if (gi < 256) ((float4*)gl)[gi] = z;
            else          ((float4*)gy)[gi - 256] = z;
        }
        if (gi < (M + 3) / 4) ((float4*)nrm)[gi] = z;

        const int rbase = b * 32;
        const int rows = min(32, M - rbase);
        #pragma unroll
        for (int it = 0; it < 8; ++it) {
            int flat = it * 256 + t;
            int row = flat >> 6;
            int k = (flat & 63) * 4;
            if (row < rows) {
                int grow = rbase + row;
                const float* src = (grow < nsubrow)
                    ? subx + (size_t)grow * 256 + k
                    : x + (size_t)(grow - nsubrow) * 256 + k;
                float4 v = *(const float4*)src;
                unsigned short h0 = f2bf(v.x), h1 = f2bf(v.y), h2 = f2bf(v.z), h3 = f2bf(v.w);
                uint2 hp;
                hp.x = ((unsigned)h1 << 16) | h0;  hp.y = ((unsigned)h3 << 16) | h2;
                int chunk = (row >> 4) * 8 + (k >> 5);
                int lne = (row & 15) | (((k >> 3) & 3) << 4);
                *(uint2*)&sX[chunk * 512 + lne * 8 + (k & 7)] = hp;
            }
        }
        __syncthreads();
        const int cvalid = (rows >> 4) * 8;
        const size_t base = (size_t)rbase * 256;
        #pragma unroll
        for (int it = 0; it < 4; ++it) {
            int flat = it * 256 + t;
            if ((flat >> 6) < cvalid)
                *(bf16x8*)&XF[base + flat * 8] = *(const bf16x8*)&sX[flat * 8];
        }
    } else if (b < nsplitblk + 512) {
        int idx = (b - nsplitblk) * 256 + t;
        int n = idx >> 8, k = idx & 255;
        float w = W1[(size_t)k * 512 + n];
        int chunk = (n >> 4) * 8 + (k >> 5);
        int lne = (n & 15) | (((k >> 3) & 3) << 4);
        w1h[chunk * 512 + lne * 8 + (k & 7)] = f2bf(w);
    } else {
        int idx = (b - nsplitblk - 512) * 256 + t;
        int n = idx >> 9, k = idx & 511;
        float w = W2[(size_t)k * 128 + n];
        int chunk = (n >> 4) * 16 + (k >> 5);
        int lne = (n & 15) | (((k >> 3) & 3) << 4);
        w2h[chunk * 512 + lne * 8 + (k & 7)] = f2bf(w);
    }
}

// ---------------------------------------------------------------------------
// Fused MLP: both layers in one kernel; A-fragments converted from raw f32
// in-register (bit-identical f2bf => absmax unchanged). z1 lives in a 64KB
// XOR-swizzled LDS tile; W1/W2 bf16 frags stream through a 2x32KB double
// buffer with counted vmcnt(8). nrm: direct store.
// ---------------------------------------------------------------------------
static __device__ __forceinline__ void stage_chunk(
    unsigned short* dst, const unsigned short* w1f, const unsigned short* w2f,
    int s, int wave, int lane)
{
    #pragma unroll
    for (int q = 0; q < 8; ++q) {
        int fl = wave * 8 + q;
        const unsigned short* src;
        if (s < 8) src = w1f + (size_t)s * 16384 + fl * 512;              // 64n W1 slice
        else       src = w2f + ((size_t)((fl & 7) * 16 + (s - 8) * 4 + (fl >> 3))) * 512; // 4-kslice W2
        async16(dst + fl * 512, src + lane * 8);
    }
}

__global__ __launch_bounds__(256) void mlp_fused(
    const float* __restrict__ subx, const float* __restrict__ x,
    const unsigned short* __restrict__ W1F,
    const unsigned short* __restrict__ W2F,
    const float* __restrict__ b1, const float* __restrict__ b2,
    unsigned short* __restrict__ embF, float* __restrict__ nrm,
    int M, int nsub)
{
    extern __shared__ __align__(16) char smem[];       // 131072 B dynamic
    unsigned short* buf0 = (unsigned short*)(smem + 65536);
    unsigned short* buf1 = (unsigned short*)(smem + 65536 + 32768);

    const int t = threadIdx.x, wave = t >> 6, lane = t & 63;
    const int quad = lane >> 4, lq = lane & 15;
    const int m0 = blockIdx.x * 64;
    const int lastch = (M >> 4) - 1;
    const int mh = wave >> 1, np = wave & 1;

    // ---- preloads: direct f32 -> bf16 fragment conversion (no XF).
    bf16x8 fA[2][8];
    #pragma unroll
    for (int mi = 0; mi < 2; ++mi) {
        int gmc = min((m0 >> 4) + mh * 2 + mi, lastch);
        int grow = gmc * 16 + lq;
        const float* src = (grow < nsub)
            ? subx + (size_t)grow * 256
            : x + (size_t)(grow - nsub) * 256;
        #pragma unroll
        for (int kc = 0; kc < 8; ++kc) {
            const float* p = src + kc * 32 + quad * 8;
            float4 v0 = *(const float4*)p;
            float4 v1 = *(const float4*)(p + 4);
            fA[mi][kc] = (bf16x8){
                (short)f2bf(v0.x), (short)f2bf(v0.y), (short)f2bf(v0.z), (short)f2bf(v0.w),
                (short)f2bf(v1.x), (short)f2bf(v1.y), (short)f2bf(v1.z), (short)f2bf(v1.w)};
        }
    }
    float b1v[16];
    #pragma unroll
    for (int i = 0; i < 16; ++i)
        b1v[i] = b1[(i >> 1) * 64 + (np * 2 + (i & 1)) * 16 + lq];
    float b2v[8];
    #pragma unroll
    for (int i = 0; i < 8; ++i) b2v[i] = b2[i * 16 + lq];

    f32x4 acc2[8];
    #pragma unroll
    for (int i = 0; i < 8; ++i) acc2[i] = (f32x4){0.f, 0.f, 0.f, 0.f};

    __syncthreads();   // drains preload vmcnt to 0; in-loop vmcnt counting exact

    stage_chunk(buf0, W1F, W2F, 0, wave, lane);
    #pragma unroll
    for (int c = 0; c < 12; ++c) {
        if (c < 11) {
            stage_chunk(((c + 1) & 1) ? buf1 : buf0, W1F, W2F, c + 1, wave, lane);
            asm volatile("s_waitcnt vmcnt(8)" ::: "memory");   // chunk c landed
        } else {
            asm volatile("s_waitcnt vmcnt(0)" ::: "memory");
        }
        __builtin_amdgcn_s_barrier();
        const unsigned short* sW = (c & 1) ? buf1 : buf0;

        if (c < 8) {
            // ---- layer 1: z1[:, c*64 .. c*64+64) = relu(X@W1^T + b1)
            f32x4 a1[2][2];
            #pragma unroll
            for (int mi = 0; mi < 2; ++mi)
                #pragma unroll
                for (int nl = 0; nl < 2; ++nl) a1[mi][nl] = (f32x4){0.f, 0.f, 0.f, 0.f};
            __builtin_amdgcn_s_setprio(1);
            #pragma unroll
            for (int kc = 0; kc < 8; ++kc) {
                #pragma unroll
                for (int nl = 0; nl < 2; ++nl) {
                    bf16x8 fB = *(const bf16x8*)&sW[((np * 2 + nl) * 8 + kc) * 512 + lane * 8];
                    #pragma unroll
                    for (int mi = 0; mi < 2; ++mi)
                        a1[mi][nl] = __builtin_amdgcn_mfma_f32_16x16x32_bf16(
                            fA[mi][kc], fB, a1[mi][nl], 0, 0, 0);
                }
            }
            __builtin_amdgcn_s_setprio(0);
            #pragma unroll
            for (int mi = 0; mi < 2; ++mi) {
                #pragma unroll
                for (int nl = 0; nl < 2; ++nl) {
                    int col = c * 64 + (np * 2 + nl) * 16 + lq;
                    #pragma unroll
                    for (int r = 0; r < 4; ++r) {
                        int row = (mh * 2 + mi) * 16 + quad * 4 + r;
                        float v = fmaxf(a1[mi][nl][r] + b1v[c * 2 + nl], 0.f);
                        int off = (row * 1024 + col * 2) ^ ((row & 7) << 4);
                        *(unsigned short*)(smem + off) = f2bf(v);
                    }
                }
            }
        } else {
            // ---- layer 2: acc2 += z1[rows, kq] @ W2^T[:, kq]
            const int Q = c - 8;
            const int row = wave * 16 + lq;
            const int sw = (row & 7) << 4;
            __builtin_amdgcn_s_setprio(1);
            #pragma unroll
            for (int gs = 0; gs < 4; ++gs) {
                int k2c = Q * 4 + gs;
                int offa = (row * 1024 + (k2c * 32 + quad * 8) * 2) ^ sw;
                bf16x8 a2 = *(const bf16x8*)(smem + offa);
                #pragma unroll
                for (int nc = 0; nc < 8; ++nc) {
                    bf16x8 fB = *(const bf16x8*)&sW[(gs * 8 + nc) * 512 + lane * 8];
                    acc2[nc] = __builtin_amdgcn_mfma_f32_16x16x32_bf16(a2, fB, acc2[nc], 0, 0, 0);
                }
            }
            __builtin_amdgcn_s_setprio(0);
        }
        asm volatile("s_waitcnt lgkmcnt(0)" ::: "memory");
        __builtin_amdgcn_s_barrier();
    }

    // ---- epilogue: bias2+relu -> ctile -> frag-order emb + nrm
    __syncthreads();
    unsigned short* ct = (unsigned short*)smem;   // [64][136] bf16
    #pragma unroll
    for (int nc = 0; nc < 8; ++nc) {
        #pragma unroll
        for (int r = 0; r < 4; ++r) {
            int row = wave * 16 + quad * 4 + r;
            float v = fmaxf(acc2[nc][r] + b2v[nc], 0.f);
            ct[row * 136 + nc * 16 + lq] = f2bf(v);
        }
    }
    __syncthreads();
    #pragma unroll
    for (int it = 0; it < 4; ++it) {
        int flat = it * 256 + t;
        int lc = flat >> 6, l = flat & 63;
        int mcl = lc >> 2, kc = lc & 3;
        int gmc2 = (m0 >> 4) + mcl;
        if (gmc2 * 16 < M) {
            bf16x8 v = *(const bf16x8*)&ct[(mcl * 16 + (l & 15)) * 136 + kc * 32 + (l >> 4) * 8];
            *(bf16x8*)&embF[((size_t)gmc2 * 4 + kc) * 512 + l * 8] = v;
        }
    }
    if (t < 64) {
        int gm = m0 + t;
        if (gm < M) {
            float s = 0.f;
            #pragma unroll
            for (int seg = 0; seg < 16; ++seg) {
                bf16x8 v = *(const bf16x8*)&ct[t * 136 + seg * 8];
                #pragma unroll
                for (int e = 0; e < 8; ++e) {
                    float f = bf2f((unsigned short)v[e]);
                    s = fmaf(f, f, s);
                }
            }
            nrm[gm] = s;
        }
    }
}

// ---------------------------------------------------------------------------
// Fallback GEMMs (unchanged; used only if 128KB dynamic-LDS opt-in fails).
// ---------------------------------------------------------------------------
__global__ __launch_bounds__(256) void gemm_l1(
    const unsigned short* __restrict__ XF,
    const unsigned short* __restrict__ BhF,
    const float* __restrict__ bias, unsigned short* __restrict__ z1F, int M)
{
    __shared__ __align__(16) unsigned short sB[16384];

    const int nb = gridDim.x;
    const int per = nb >> 3, rem = nb & 7;
    const int xcd = blockIdx.x & 7, slot = blockIdx.x >> 3;
    const int newbid = xcd * per + min(xcd, rem) + slot;
    const int m0 = (newbid >> 3) * 128, n0 = (newbid & 7) * 64;

    const int t = threadIdx.x, wave = t >> 6, lane = t & 63;
    const int quad = lane >> 4, lq = lane & 15;
    const int lastch = (M >> 4) - 1;

    #pragma unroll
    for (int q = 0; q < 8; ++q) {
        int c = wave * 8 + q;
        int nc = c >> 3, kc = c & 7;
        const unsigned short* src = BhF
            + ((size_t)((n0 >> 4) + nc)) * 4096 + kc * 512 + lane * 8;
        async16(sB + c * 512, src);
    }

    const unsigned short* pA[2];
    #pragma unroll
    for (int mi = 0; mi < 2; ++mi) {
        int mc = min((m0 >> 4) + wave * 2 + mi, lastch);
        pA[mi] = XF + (size_t)mc * 4096 + lane * 8;
    }

    f32x4 acc[2][4];
    #pragma unroll
    for (int i = 0; i < 2; ++i)
        #pragma unroll
        for (int j = 0; j < 4; ++j) acc[i][j] = (f32x4){0.f, 0.f, 0.f, 0.f};

    __syncthreads();

    #pragma unroll
    for (int kc = 0; kc < 8; ++kc) {
        bf16x8 fA[2];
        #pragma unroll
        for (int mi = 0; mi < 2; ++mi)
            fA[mi] = *(const bf16x8*)(pA[mi] + kc * 512);
        #pragma unroll
        for (int ni = 0; ni < 4; ++ni) {
            bf16x8 fB = *(const bf16x8*)&sB[(ni * 8 + kc) * 512 + lane * 8];
            #pragma unroll
            for (int mi = 0; mi < 2; ++mi)
                acc[mi][ni] = __builtin_amdgcn_mfma_f32_16x16x32_bf16(fA[mi], fB, acc[mi][ni], 0, 0, 0);
        }
    }

    __syncthreads();
    unsigned short* ctile = sB;
    float bv[4];
    #pragma unroll
    for (int ni = 0; ni < 4; ++ni) bv[ni] = bias[n0 + ni * 16 + lq];
    #pragma unroll
    for (int mi = 0; mi < 2; ++mi)
        #pragma unroll
        for (int ni = 0; ni < 4; ++ni)
            #pragma unroll
            for (int r = 0; r < 4; ++r) {
                float v = fmaxf(acc[mi][ni][r] + bv[ni], 0.f);
                ctile[(wave * 32 + mi * 16 + quad * 4 + r) * 72 + ni * 16 + lq] = f2bf(v);
            }
    __syncthreads();
    #pragma unroll
    for (int it = 0; it < 4; ++it) {
        int flat = it * 256 + t;
        int c = flat >> 6, l = flat & 63;
        int mcl = c >> 1, kc2 = c & 1;
        int gmc = (m0 >> 4) + mcl;
        if (gmc * 16 < M) {
            bf16x8 v = *(const bf16x8*)&ctile[(mcl * 16 + (l & 15)) * 72 + kc2 * 32 + (l >> 4) * 8];
            *(bf16x8*)&z1F[((size_t)gmc * 16 + (n0 >> 5) + kc2) * 512 + l * 8] = v;
        }
    }
}

__global__ __launch_bounds__(256) void gemm_l2_norm(
    const unsigned short* __restrict__ AF,
    const unsigned short* __restrict__ BhF,
    const float* __restrict__ bias, unsigned short* __restrict__ embF,
    float* __restrict__ nrm, int M)
{
    __shared__ __align__(16) unsigned short sB[18432];

    const int nb = gridDim.x;
    const int per = nb >> 3, rem = nb & 7;
    const int xcd = blockIdx.x & 7, slot = blockIdx.x >> 3;
    const int newbid = xcd * per + min(xcd, rem) + slot;
    const int m0 = (newbid >> 2) * 256, n0 = (newbid & 3) * 32;

    const int t = threadIdx.x, wave = t >> 6, lane = t & 63;
    const int quad = lane >> 4, lq = lane & 15;
    const int lastch = (M >> 4) - 1;

    #pragma unroll
    for (int q = 0; q < 8; ++q) {
        int c = wave * 8 + q;
        int nc = c >> 4, kc = c & 15;
        const unsigned short* src = BhF
            + ((size_t)((n0 >> 4) + nc)) * 8192 + kc * 512 + lane * 8;
        async16(sB + c * 512, src);
    }

    const unsigned short* pA[4];
    #pragma unroll
    for (int mi = 0; mi < 4; ++mi) {
        int mc = min((m0 >> 4) + wave * 4 + mi, lastch);
        pA[mi] = AF + (size_t)mc * 8192 + lane * 8;
    }

    f32x4 acc[4][2];
    #pragma unroll
    for (int i = 0; i < 4; ++i)
        #pragma unroll
        for (int j = 0; j < 2; ++j) acc[i][j] = (f32x4){0.f, 0.f, 0.f, 0.f};

    __syncthreads();

    #pragma unroll 4
    for (int kc = 0; kc < 16; ++kc) {
        bf16x8 fA[4];
        #pragma unroll
        for (int mi = 0; mi < 4; ++mi)
            fA[mi] = *(const bf16x8*)(pA[mi] + kc * 512);
        #pragma unroll
        for (int ni = 0; ni < 2; ++ni) {
            bf16x8 fB = *(const bf16x8*)&sB[(ni * 16 + kc) * 512 + lane * 8];
            #pragma unroll
            for (int mi = 0; mi < 4; ++mi)
                acc[mi][ni] = __builtin_amdgcn_mfma_f32_16x16x32_bf16(fA[mi], fB, acc[mi][ni], 0, 0, 0);
        }
    }

    __syncthreads();
    unsigned short* ctile = sB;
    float bv[2];
    #pragma unroll
    for (int ni = 0; ni < 2; ++ni) bv[ni] = bias[n0 + ni * 16 + lq];
    #pragma unroll
    for (int mi = 0; mi < 4; ++mi)
        #pragma unroll
        for (int ni = 0; ni < 2; ++ni)
            #pragma unroll
            for (int r = 0; r < 4; ++r) {
                float v = fmaxf(acc[mi][ni][r] + bv[ni], 0.f);
                ctile[(wave * 64 + mi * 16 + quad * 4 + r) * 36 + ni * 16 + lq] = f2bf(v);
            }
    __syncthreads();

    #pragma unroll
    for (int it = 0; it < 4; ++it) {
        int flat = it * 256 + t;
        int c = flat >> 6, l = flat & 63;
        int gmc = (m0 >> 4) + c;
        if (gmc * 16 < M) {
            bf16x8 v = *(const bf16x8*)&ctile[(c * 16 + (l & 15)) * 36 + (l >> 4) * 8];
            *(bf16x8*)&embF[((size_t)gmc * 4 + (n0 >> 5)) * 512 + l * 8] = v;
        }
    }
    int gm = m0 + t;
    if (gm < M) {
        float s = 0.f;
        #pragma unroll
        for (int seg = 0; seg < 4; ++seg) {
            bf16x8 v = *(const bf16x8*)&ctile[t * 36 + seg * 8];
            #pragma unroll
            for (int e = 0; e < 8; ++e) {
                float f = bf2f((unsigned short)v[e]);
                s = fmaf(f, f, s);
            }
        }
        atomicAdd(&nrm[gm], s);
    }
}

// ---------------------------------------------------------------------------
// Flash NCA (R1 version: NO device fence, NO folded finalize).
// ---------------------------------------------------------------------------
__global__ __launch_bounds__(256) void nca_flash_mfma(
    const unsigned short* __restrict__ embF, const float* __restrict__ nrm,
    const float* __restrict__ y, float* __restrict__ gl, float* __restrict__ gy,
    int N, int jspan)
{
    __shared__ __align__(16) unsigned short sB[16384];
    __shared__ float s2s[128], ys[128];

    const int t = threadIdx.x, wave = t >> 6, lane = t & 63;
    const int quad = lane >> 4, lq = lane & 15;
    const int i0 = blockIdx.x * 64;
    const int j0base = blockIdx.y * jspan;
    const int jend = min(j0base + jspan, N);

    bf16x8 fa[4];
    const int hc = ((N + i0) >> 4) + wave;
    #pragma unroll
    for (int kk = 0; kk < 4; ++kk)
        fa[kk] = *(const bf16x8*)&embF[((size_t)hc * 4 + kk) * 512 + lane * 8];
    float myh2[4];
    #pragma unroll
    for (int r = 0; r < 4; ++r) myh2[r] = nrm[N + i0 + wave * 16 + quad * 4 + r];

    float lacc[4] = {0.f, 0.f, 0.f, 0.f};
    float yacc[4] = {0.f, 0.f, 0.f, 0.f};

    for (int j0 = j0base; j0 < jend; j0 += 128) {
        __syncthreads();
        #pragma unroll
        for (int q = 0; q < 8; ++q) {
            int c = wave * 8 + q;
            async16(sB + c * 512,
                    embF + ((size_t)(j0 >> 4) * 4 + c) * 512 + lane * 8);
        }
        if (t < 128) {
            int j = j0 + t;
            s2s[t] = (j < jend) ? nrm[j] : 1e30f;   // OOB -> p = 0
            ys[t]  = (j < jend) ? y[j] : 0.f;
        }
        __syncthreads();

        f32x4 acc[8];
        #pragma unroll
        for (int jt = 0; jt < 8; ++jt) acc[jt] = (f32x4){0.f, 0.f, 0.f, 0.f};
        #pragma unroll
        for (int kk = 0; kk < 4; ++kk) {
            #pragma unroll
            for (int jt = 0; jt < 8; ++jt) {
                bf16x8 b = *(const bf16x8*)&sB[(jt * 4 + kk) * 512 + lane * 8];
                acc[jt] = __builtin_amdgcn_mfma_f32_16x16x32_bf16(fa[kk], b, acc[jt], 0, 0, 0);
            }
        }

        #pragma unroll
        for (int jt = 0; jt < 8; ++jt) {
            int col = jt * 16 + lq;
            float ss = s2s[col];
            float sy = ys[col];
            #pragma unroll
            for (int r = 0; r < 4; ++r) {
                float d2 = myh2[r] + ss - 2.f * acc[jt][r];
                float d  = sqrtf(fmaxf(d2, 0.f) + EPSF);
                float p  = __expf(-d);
                lacc[r] += p;
                yacc[r]  = fmaf(p, sy, yacc[r]);
            }
        }
    }

    #pragma unroll
    for (int r = 0; r < 4; ++r) {
        #pragma unroll
        for (int off = 8; off > 0; off >>= 1) {
            lacc[r] += __shfl_down(lacc[r], off, 16);
            yacc[r] += __shfl_down(yacc[r], off, 16);
        }
    }
    if (lq == 0) {
        int row = i0 + wave * 16 + quad * 4;
        #pragma unroll
        for (int r = 0; r < 4; ++r) {
            atomicAdd(&gl[row + r], lacc[r]);
            atomicAdd(&gy[row + r], yacc[r]);
        }
    }
}

__global__ __launch_bounds__(256) void finalize_div(
    const float* __restrict__ gl, const float* __restrict__ gy,
    float* __restrict__ out, int B)
{
    int i = blockIdx.x * 256 + threadIdx.x;
    if (i < B) out[i] = gy[i] / gl[i];
}

// ---------------------------------------------------------------------------
static int g_fused_ok = -1;

extern "C" void kernel_launch(void* const* d_in, const int* in_sizes, int n_in,
                              void* d_out, int out_size, void* d_ws, size_t ws_size,
                              hipStream_t stream)
{
    const float* x    = (const float*)d_in[0];  // [1024,256]
    const float* subx = (const float*)d_in[1];  // [30000,256]
    const float* suby = (const float*)d_in[2];  // [30000]
    const float* W1   = (const float*)d_in[3];  // [256,512]
    const float* b1   = (const float*)d_in[4];  // [512]
    const float* W2   = (const float*)d_in[5];  // [512,128]
    const float* b2   = (const float*)d_in[6];  // [128]
    float* out = (float*)d_out;                 // [1024]

    const int B = 1024, N = 30000, D = 256, H1 = 512, H2 = 128;
    const int M = N + B;  // 31024

    char* wsb = (char*)d_ws;
    size_t off = 0;
    auto alloc = [&](size_t bytes) -> char* {
        char* p = wsb + off;
        off += (bytes + 255) & ~(size_t)255;
        return p;
    };
    unsigned short* cx   = (unsigned short*)alloc((size_t)M * D * 2);   // fallback only
    unsigned short* w1hT = (unsigned short*)alloc((size_t)H1 * D * 2);
    unsigned short* w2hT = (unsigned short*)alloc((size_t)H2 * H1 * 2);
    unsigned short* z1   = (unsigned short*)alloc((size_t)M * H1 * 2);  // fallback only
    unsigned short* emb  = (unsigned short*)alloc((size_t)M * H2 * 2);
    float* nrm = (float*)alloc((size_t)M * 4);
    float* gl  = (float*)alloc((size_t)B * 4);
    float* gy  = (float*)alloc((size_t)B * 4);
    (void)ws_size; (void)in_sizes; (void)n_in; (void)out_size;

    if (g_fused_ok < 0) {
        hipError_t e = hipFuncSetAttribute((const void*)mlp_fused,
            hipFuncAttributeMaxDynamicSharedMemorySize, 131072);
        g_fused_ok = (e == hipSuccess) ? 1 : 0;
    }

    dim3 blk(256);
    const int JSPAN = 512;
    const int NSPLIT = (N + JSPAN - 1) / JSPAN;  // 59

    if (g_fused_ok) {
        prep_slim<<<dim3(769), blk, 0, stream>>>(W1, W2, w1hT, w2hT, gl, gy);
        mlp_fused<<<dim3((M + 63) / 64), blk, 131072, stream>>>(
            subx, x, w1hT, w2hT, b1, b2, emb, nrm, M, N);
    } else {
        const int NSPLITBLK = (M + 31) / 32;                 // 970
        prep_full<<<dim3(NSPLITBLK + 512 + 256), blk, 0, stream>>>(
            subx, x, W1, W2, cx, w1hT, w2hT, gl, gy, nrm, M, N, NSPLITBLK);
        gemm_l1<<<dim3(((M + 127) / 128) * (H1 / 64)), blk, 0, stream>>>(
            cx, w1hT, b1, z1, M);
        gemm_l2_norm<<<dim3(((M + 255) / 256) * (H2 / 32)), blk, 0, stream>>>(
            z1, w2hT, b2, emb, nrm, M);
    }

    nca_flash_mfma<<<dim3(B / 64, NSPLIT), blk, 0, stream>>>(
        emb, nrm, suby, gl, gy, N, JSPAN);
    finalize_div<<<dim3(B / 256), blk, 0, stream>>>(gl, gy, out, B);
}